// Round 8
// baseline (65.190 us; speedup 1.0000x reference)
//
#include <hip/hip_runtime.h>
#include <hip/hip_bf16.h>

#define N_TOK   32768       // 8 * 4096 tokens
#define DPROJ   1024
#define SCALE   32.0f       // sqrt(1024)

typedef short bf16x8 __attribute__((ext_vector_type(8)));
typedef float f32x4  __attribute__((ext_vector_type(4)));

__device__ __forceinline__ short f2bf(float f) {
    unsigned u = __builtin_bit_cast(unsigned, f);
    unsigned r = (u + 0x7FFFu + ((u >> 16) & 1u)) >> 16;   // RNE
    return (short)r;
}

// ---------------------------------------------------------------------------
// Fused prep kernel.
//   blocks [0,128):   bucketize (wave-ballot aggregated, 4 atomics per wave)
//   blocks [128,896): transpose+convert proj -> projT[n][k] bf16
// ---------------------------------------------------------------------------
__global__ void k_prep(const int* __restrict__ inp, int* __restrict__ cnt,
                       int* __restrict__ perm, int* __restrict__ rowidx,
                       const float* __restrict__ p0, const float* __restrict__ p1,
                       const float* __restrict__ p2, const float* __restrict__ p3,
                       short* __restrict__ t0, short* __restrict__ t1,
                       short* __restrict__ t2, short* __restrict__ t3)
{
    __shared__ float tile[128][17];

    if (blockIdx.x < 128) {
        // ---------------- bucketize ----------------
        int i = blockIdx.x * 256 + threadIdx.x;
        int t = inp[i];
        int b, l;
        if (t < 20000)       { b = 0; l = 0; }
        else if (t < 40000)  { b = 1; l = 20000; }
        else if (t < 200000) { b = 2; l = 40000; }
        else                 { b = 3; l = 200000; }

        unsigned long long m0 = __ballot(b == 0);
        unsigned long long m1 = __ballot(b == 1);
        unsigned long long m2 = __ballot(b == 2);
        unsigned long long m3 = __ballot(b == 3);

        int lane = threadIdx.x & 63;
        int mybase = 0;
        if (lane < 4) {
            unsigned long long mm = (lane == 0) ? m0 : (lane == 1) ? m1 : (lane == 2) ? m2 : m3;
            mybase = atomicAdd(&cnt[lane], __popcll(mm));
        }
        int base = __shfl(mybase, b);
        unsigned long long mine = (b == 0) ? m0 : (b == 1) ? m1 : (b == 2) ? m2 : m3;
        unsigned long long lt = (lane == 0) ? 0ull : (~0ull >> (64 - lane));
        int pos = base + __popcll(mine & lt);
        perm[b * N_TOK + pos]   = i;
        rowidx[b * N_TOK + pos] = t - l;
        return;
    }

    // ---------------- transpose ----------------
    int bid = blockIdx.x - 128;
    const float* src; short* dst; int K; int rel;
    if (bid < 512)      { src = p0; dst = t0; K = 1024; rel = bid; }
    else if (bid < 640) { src = p1; dst = t1; K = 256;  rel = bid - 512; }
    else if (bid < 704) { src = p2; dst = t2; K = 64;   rel = bid - 640; }
    else                { src = p3; dst = t3; K = 16;   rel = bid - 704; }
    int ktiles = (K + 127) >> 7;
    int k0 = (rel % ktiles) * 128;
    int n0 = (rel / ktiles) * 16;
    int t = threadIdx.x;

    #pragma unroll
    for (int i = 0; i < 2; ++i) {
        int idx = t + i * 256;          // 0..511
        int k = idx >> 2;               // 0..127
        int nc = (idx & 3) * 4;         // 0,4,8,12
        if (k0 + k < K) {
            float4 v = *reinterpret_cast<const float4*>(src + (size_t)(k0 + k) * DPROJ + n0 + nc);
            tile[k][nc + 0] = v.x; tile[k][nc + 1] = v.y;
            tile[k][nc + 2] = v.z; tile[k][nc + 3] = v.w;
        }
    }
    __syncthreads();
    int n  = t >> 4;                    // 0..15
    int kc = (t & 15) * 8;              // 0..120
    if (k0 + kc < K) {
        short s[8];
        #pragma unroll
        for (int j = 0; j < 8; ++j) s[j] = f2bf(tile[kc + j][n]);
        *reinterpret_cast<int4*>(dst + (size_t)(n0 + n) * K + k0 + kc) =
            *reinterpret_cast<const int4*>(s);
    }
}

// ---------------------------------------------------------------------------
// Fused gathered bf16-MFMA GEMM over all buckets.
// BM=64, BN=256, BK=32; 256 threads / 4 waves, wave-tile 64x64 (4x4 frags).
// B is NOT staged in LDS: each wave reads only its own columns (no sharing),
// and B is L2-resident -> B-frags load per-lane direct from transposed bt
// (4 lanes x 64B contiguous per row). A stays in LDS (8-way... 4-wave reuse),
// double-buffered -> ONE barrier per K-step. A global loads issue early (T14).
// Grid 4x520, XCD remap: all 4 n-panels of a row-tile on the same XCD.
// ---------------------------------------------------------------------------
__global__ __launch_bounds__(256, 3) void k_gemm(
    const float* __restrict__ e0, const float* __restrict__ e1,
    const float* __restrict__ e2, const float* __restrict__ e3,
    const short* __restrict__ t0, const short* __restrict__ t1,
    const short* __restrict__ t2, const short* __restrict__ t3,
    const int* __restrict__ cnt, const int* __restrict__ perm,
    const int* __restrict__ rowidx, float* __restrict__ out)
{
    __shared__ short As[2][64][40];     // 2 x 5KB, stride 80B (bank-uniform b128)

    // ---- dispatch-id -> (ytile, panel), XCD-grouped ----
    const int hw     = blockIdx.y * 4 + blockIdx.x;   // HW dispatch order (x fastest)
    const int ytile  = (hw >> 5) * 8 + (hw & 7);
    const int panel  = (hw >> 3) & 3;

    const int c0 = cnt[0], c1 = cnt[1], c2 = cnt[2], c3 = cnt[3];
    const int q0 = (c0 + 63) & ~63;
    const int q1 = q0 + ((c1 + 63) & ~63);
    const int q2 = q1 + ((c2 + 63) & ~63);
    const int q3 = q2 + ((c3 + 63) & ~63);
    const int p0 = ytile * 64;
    if (p0 >= q3) return;
    int b, M, m0, K; const float* emb; const short* bt;
    if (p0 < q0)      { b = 0; M = c0; m0 = p0;      K = 1024; emb = e0; bt = t0; }
    else if (p0 < q1) { b = 1; M = c1; m0 = p0 - q0; K = 256;  emb = e1; bt = t1; }
    else if (p0 < q2) { b = 2; M = c2; m0 = p0 - q1; K = 64;   emb = e2; bt = t2; }
    else              { b = 3; M = c3; m0 = p0 - q2; K = 16;   emb = e3; bt = t3; }
    if (m0 >= M) return;
    const int* pperm = perm   + b * N_TOK;
    const int* prow  = rowidx + b * N_TOK;

    const int tid  = threadIdx.x;
    const int lane = tid & 63;
    const int w    = tid >> 6;          // 0..3
    const int n0   = panel * 256;

    // ---- A staging indices: 64 rows x 32 k, 8 floats per thread ----
    const int sr = tid >> 2;            // 0..63
    const int sc = (tid & 3) * 8;       // 0,8,16,24 (elements)
    const bool avalid = (m0 + sr) < M;
    const int  arow   = avalid ? prow[m0 + sr] : 0;
    const float* aptr = emb + (size_t)arow * K;

    f32x4 acc[4][4];
    #pragma unroll
    for (int mi = 0; mi < 4; ++mi)
        #pragma unroll
        for (int ni = 0; ni < 4; ++ni) acc[mi][ni] = (f32x4)0.0f;

    const int koff = (lane >> 4) * 8;   // same k-bijection for A and B frags
    const int fr   = lane & 15;
    const short* btw = bt + (size_t)(n0 + w * 64 + fr) * K;   // + ni*16*K + k

    float av[8];
#define ISSUE_A(K0)                                                            \
    {                                                                          \
        _Pragma("unroll")                                                      \
        for (int j = 0; j < 8; ++j) av[j] = 0.0f;                              \
        if (avalid && ((K0) + sc) < K) {                                       \
            float4 x = *reinterpret_cast<const float4*>(aptr + (K0) + sc);     \
            float4 y = *reinterpret_cast<const float4*>(aptr + (K0) + sc + 4); \
            av[0] = x.x; av[1] = x.y; av[2] = x.z; av[3] = x.w;                \
            av[4] = y.x; av[5] = y.y; av[6] = y.z; av[7] = y.w;                \
        }                                                                      \
    }
#define WRITE_A(BUF)                                                           \
    {                                                                          \
        short asv[8];                                                          \
        _Pragma("unroll")                                                      \
        for (int j = 0; j < 8; ++j) asv[j] = f2bf(av[j]);                      \
        *reinterpret_cast<int4*>(&As[BUF][sr][sc]) =                           \
            *reinterpret_cast<const int4*>(asv);                               \
    }

    // prologue: stage K-step 0 into buffer 0
    ISSUE_A(0);
    WRITE_A(0);
    __syncthreads();

    int cur = 0;
    for (int k0 = 0; k0 < K; k0 += 32, cur ^= 1) {
        const bool more = (k0 + 32) < K;
        if (more) ISSUE_A(k0 + 32);             // issue-early: hide under MFMA

        // ---- B frags direct from global (L2-resident) ----
        bf16x8 bfr[4];
        #pragma unroll
        for (int ni = 0; ni < 4; ++ni) {
            if ((k0 + koff) < K)                // only K=16 trips this guard
                bfr[ni] = *reinterpret_cast<const bf16x8*>(
                    btw + (size_t)ni * 16 * K + k0 + koff);
            else
                bfr[ni] = (bf16x8)0;
        }
        bf16x8 afr[4];
        #pragma unroll
        for (int mi = 0; mi < 4; ++mi)
            afr[mi] = *reinterpret_cast<const bf16x8*>(&As[cur][mi * 16 + fr][koff]);

        #pragma unroll
        for (int mi = 0; mi < 4; ++mi)
            #pragma unroll
            for (int ni = 0; ni < 4; ++ni)
                acc[mi][ni] = __builtin_amdgcn_mfma_f32_16x16x32_bf16(
                    afr[mi], bfr[ni], acc[mi][ni], 0, 0, 0);

        if (more) WRITE_A(cur ^ 1);             // other buffer: no read hazard
        __syncthreads();                        // one barrier per K-step
    }
#undef ISSUE_A
#undef WRITE_A

    // ---- epilogue: C/D layout col=lane&15, row=(lane>>4)*4+reg ----
    const int colb = n0 + w * 64 + fr;
    const int rowg = (lane >> 4) * 4;
    #pragma unroll
    for (int mi = 0; mi < 4; ++mi) {
        #pragma unroll
        for (int j = 0; j < 4; ++j) {
            int m = m0 + mi * 16 + rowg + j;
            if (m < M) {
                size_t r = (size_t)pperm[m] * DPROJ + colb;
                out[r]      = acc[mi][0][j] * SCALE;
                out[r + 16] = acc[mi][1][j] * SCALE;
                out[r + 32] = acc[mi][2][j] * SCALE;
                out[r + 48] = acc[mi][3][j] * SCALE;
            }
        }
    }
}

// ---------------------------------------------------------------------------
// Fallback (ws too small): one block per token, direct fp32 dot products.
// ---------------------------------------------------------------------------
__global__ void k_naive(const int* __restrict__ inp,
                        const float* __restrict__ emb0, const float* __restrict__ emb1,
                        const float* __restrict__ emb2, const float* __restrict__ emb3,
                        const float* __restrict__ proj0, const float* __restrict__ proj1,
                        const float* __restrict__ proj2, const float* __restrict__ proj3,
                        float* __restrict__ out)
{
    __shared__ float e[1024];
    int t = inp[blockIdx.x];
    const float* emb; const float* proj; int K, l;
    if (t < 20000)       { emb = emb0; proj = proj0; K = 1024; l = 0; }
    else if (t < 40000)  { emb = emb1; proj = proj1; K = 256;  l = 20000; }
    else if (t < 200000) { emb = emb2; proj = proj2; K = 64;   l = 40000; }
    else                 { emb = emb3; proj = proj3; K = 16;   l = 200000; }
    int tid = threadIdx.x;
    for (int k = tid; k < K; k += 256) e[k] = emb[(size_t)(t - l) * K + k];
    __syncthreads();
    float acc[4] = {0.f, 0.f, 0.f, 0.f};
    for (int k = 0; k < K; ++k) {
        float ek = e[k];
        #pragma unroll
        for (int c = 0; c < 4; ++c)
            acc[c] = fmaf(ek, proj[(size_t)k * DPROJ + tid + 256 * c], acc[c]);
    }
    #pragma unroll
    for (int c = 0; c < 4; ++c)
        out[(size_t)blockIdx.x * DPROJ + tid + 256 * c] = acc[c] * SCALE;
}

extern "C" void kernel_launch(void* const* d_in, const int* in_sizes, int n_in,
                              void* d_out, int out_size, void* d_ws, size_t ws_size,
                              hipStream_t stream) {
    const int*   inp   = (const int*)d_in[0];
    const float* emb0  = (const float*)d_in[1];
    const float* proj0 = (const float*)d_in[2];
    const float* emb1  = (const float*)d_in[3];
    const float* proj1 = (const float*)d_in[4];
    const float* emb2  = (const float*)d_in[5];
    const float* proj2 = (const float*)d_in[6];
    const float* emb3  = (const float*)d_in[7];
    const float* proj3 = (const float*)d_in[8];
    float* out = (float*)d_out;

    // ws layout (256B-aligned regions)
    const size_t off_cnt  = 0;
    const size_t off_perm = 256;
    const size_t off_row  = off_perm + 4ull * N_TOK * 4;
    const size_t off_t0   = off_row  + 4ull * N_TOK * 4;
    const size_t off_t1   = off_t0 + 1024ull * 1024 * 2;
    const size_t off_t2   = off_t1 + 1024ull * 256 * 2;
    const size_t off_t3   = off_t2 + 1024ull * 64 * 2;
    const size_t needed   = off_t3 + 1024ull * 16 * 2;

    if (d_ws == nullptr || ws_size < needed) {
        k_naive<<<N_TOK, 256, 0, stream>>>(inp, emb0, emb1, emb2, emb3,
                                           proj0, proj1, proj2, proj3, out);
        return;
    }

    char* ws = (char*)d_ws;
    int*   cnt    = (int*)(ws + off_cnt);
    int*   perm   = (int*)(ws + off_perm);
    int*   rowidx = (int*)(ws + off_row);
    short* t0     = (short*)(ws + off_t0);
    short* t1     = (short*)(ws + off_t1);
    short* t2     = (short*)(ws + off_t2);
    short* t3     = (short*)(ws + off_t3);

    hipMemsetAsync(cnt, 0, 16, stream);
    k_prep<<<896, 256, 0, stream>>>(inp, cnt, perm, rowidx,
                                    proj0, proj1, proj2, proj3, t0, t1, t2, t3);

    dim3 grid(4, 520);      // 4*520 = 2080 = 65 complete mod-8 chunks (bijective remap)
    k_gemm<<<grid, 256, 0, stream>>>(emb0, emb1, emb2, emb3,
                                     t0, t1, t2, t3,
                                     cnt, perm, rowidx, out);
}

// Round 9
// 59.272 us; speedup vs baseline: 1.0998x; 1.0998x over previous
//
#include <hip/hip_runtime.h>
#include <hip/hip_bf16.h>

#define N_TOK   32768       // 8 * 4096 tokens
#define DPROJ   1024
#define SCALE   32.0f       // sqrt(1024)

typedef short bf16x8 __attribute__((ext_vector_type(8)));
typedef float f32x4  __attribute__((ext_vector_type(4)));

__device__ __forceinline__ short f2bf(float f) {
    unsigned u = __builtin_bit_cast(unsigned, f);
    unsigned r = (u + 0x7FFFu + ((u >> 16) & 1u)) >> 16;   // RNE
    return (short)r;
}

// ---------------------------------------------------------------------------
// Fused prep kernel.
//   blocks [0,128):   bucketize (wave-ballot aggregated, 4 atomics per wave)
//   blocks [128,896): transpose+convert proj -> projT[n][k] bf16
// ---------------------------------------------------------------------------
__global__ void k_prep(const int* __restrict__ inp, int* __restrict__ cnt,
                       int* __restrict__ perm, int* __restrict__ rowidx,
                       const float* __restrict__ p0, const float* __restrict__ p1,
                       const float* __restrict__ p2, const float* __restrict__ p3,
                       short* __restrict__ t0, short* __restrict__ t1,
                       short* __restrict__ t2, short* __restrict__ t3)
{
    __shared__ float tile[128][17];

    if (blockIdx.x < 128) {
        // ---------------- bucketize ----------------
        int i = blockIdx.x * 256 + threadIdx.x;
        int t = inp[i];
        int b, l;
        if (t < 20000)       { b = 0; l = 0; }
        else if (t < 40000)  { b = 1; l = 20000; }
        else if (t < 200000) { b = 2; l = 40000; }
        else                 { b = 3; l = 200000; }

        unsigned long long m0 = __ballot(b == 0);
        unsigned long long m1 = __ballot(b == 1);
        unsigned long long m2 = __ballot(b == 2);
        unsigned long long m3 = __ballot(b == 3);

        int lane = threadIdx.x & 63;
        int mybase = 0;
        if (lane < 4) {
            unsigned long long mm = (lane == 0) ? m0 : (lane == 1) ? m1 : (lane == 2) ? m2 : m3;
            mybase = atomicAdd(&cnt[lane], __popcll(mm));
        }
        int base = __shfl(mybase, b);
        unsigned long long mine = (b == 0) ? m0 : (b == 1) ? m1 : (b == 2) ? m2 : m3;
        unsigned long long lt = (lane == 0) ? 0ull : (~0ull >> (64 - lane));
        int pos = base + __popcll(mine & lt);
        perm[b * N_TOK + pos]   = i;
        rowidx[b * N_TOK + pos] = t - l;
        return;
    }

    // ---------------- transpose ----------------
    int bid = blockIdx.x - 128;
    const float* src; short* dst; int K; int rel;
    if (bid < 512)      { src = p0; dst = t0; K = 1024; rel = bid; }
    else if (bid < 640) { src = p1; dst = t1; K = 256;  rel = bid - 512; }
    else if (bid < 704) { src = p2; dst = t2; K = 64;   rel = bid - 640; }
    else                { src = p3; dst = t3; K = 16;   rel = bid - 704; }
    int ktiles = (K + 127) >> 7;
    int k0 = (rel % ktiles) * 128;
    int n0 = (rel / ktiles) * 16;
    int t = threadIdx.x;

    #pragma unroll
    for (int i = 0; i < 2; ++i) {
        int idx = t + i * 256;          // 0..511
        int k = idx >> 2;               // 0..127
        int nc = (idx & 3) * 4;         // 0,4,8,12
        if (k0 + k < K) {
            float4 v = *reinterpret_cast<const float4*>(src + (size_t)(k0 + k) * DPROJ + n0 + nc);
            tile[k][nc + 0] = v.x; tile[k][nc + 1] = v.y;
            tile[k][nc + 2] = v.z; tile[k][nc + 3] = v.w;
        }
    }
    __syncthreads();
    int n  = t >> 4;                    // 0..15
    int kc = (t & 15) * 8;              // 0..120
    if (k0 + kc < K) {
        short s[8];
        #pragma unroll
        for (int j = 0; j < 8; ++j) s[j] = f2bf(tile[kc + j][n]);
        *reinterpret_cast<int4*>(dst + (size_t)(n0 + n) * K + k0 + kc) =
            *reinterpret_cast<const int4*>(s);
    }
}

// ---------------------------------------------------------------------------
// Fused gathered bf16-MFMA GEMM over all buckets — MAX OCCUPANCY version.
// BM=64, BN=128, BK=32; 512 threads / 8 waves (2x4), wave-tile 32x32
// (acc[2][2] = 16 VGPR) -> kernel targets <=64 VGPR so 8 waves/SIMD can be
// resident (launch_bounds(512,8) = 4 blocks/CU = 32 waves = 100%).
// Grid 8x520 XCD-chunked: all 8 n-panels of a ytile land on the SAME XCD
// (dispatch ids differ by 8) -> A-tile re-reads are L2-hits. A+B in LDS,
// T14 issue-early staging, epilogue perm loads hoisted above the K-loop.
// ---------------------------------------------------------------------------
__global__ __launch_bounds__(512, 8) void k_gemm(
    const float* __restrict__ e0, const float* __restrict__ e1,
    const float* __restrict__ e2, const float* __restrict__ e3,
    const short* __restrict__ t0, const short* __restrict__ t1,
    const short* __restrict__ t2, const short* __restrict__ t3,
    const int* __restrict__ cnt, const int* __restrict__ perm,
    const int* __restrict__ rowidx, float* __restrict__ out)
{
    __shared__ short As[64][40];    // 5.1 KB  (stride 80B: b128 reads bank-clean)
    __shared__ short Bs[128][40];   // 10.2 KB

    // ---- dispatch-id -> (ytile, panel), XCD-chunked ----
    const int hw    = blockIdx.y * 8 + blockIdx.x;    // HW dispatch order (x fastest)
    const int ytile = (hw >> 6) * 8 + (hw & 7);       // 8 ytiles per 64-chunk
    const int panel = (hw >> 3) & 7;                  // panel-siblings differ by 8 -> same XCD

    const int c0 = cnt[0], c1 = cnt[1], c2 = cnt[2], c3 = cnt[3];
    const int q0 = (c0 + 63) & ~63;
    const int q1 = q0 + ((c1 + 63) & ~63);
    const int q2 = q1 + ((c2 + 63) & ~63);
    const int q3 = q2 + ((c3 + 63) & ~63);
    const int p0 = ytile * 64;
    if (p0 >= q3) return;
    int b, M, m0, K; const float* emb; const short* bt;
    if (p0 < q0)      { b = 0; M = c0; m0 = p0;      K = 1024; emb = e0; bt = t0; }
    else if (p0 < q1) { b = 1; M = c1; m0 = p0 - q0; K = 256;  emb = e1; bt = t1; }
    else if (p0 < q2) { b = 2; M = c2; m0 = p0 - q1; K = 64;   emb = e2; bt = t2; }
    else              { b = 3; M = c3; m0 = p0 - q2; K = 16;   emb = e3; bt = t3; }
    if (m0 >= M) return;
    const int* pperm = perm   + b * N_TOK;
    const int* prow  = rowidx + b * N_TOK;

    const int tid  = threadIdx.x;
    const int lane = tid & 63;
    const int w    = tid >> 6;          // 0..7
    const int wr   = w >> 2;            // 0..1  wave-row (32 rows)
    const int wc   = w & 3;             // 0..3  wave-col (32 cols)
    const int n0   = panel * 128;

    // ---- staging indices ----
    // A: 64 rows x 32 k; thread -> (row = tid>>3, 4-float chunk)
    const int ar  = tid >> 3;           // 0..63
    const int ac  = (tid & 7) * 4;      // 0..28
    const bool avalid = (m0 + ar) < M;
    const int  arow   = avalid ? prow[m0 + ar] : 0;
    const float* aptr = emb + (size_t)arow * K;
    // B: 128 rows x 32 k; thread -> (row = tid>>2, 8-short chunk)
    const int br = tid >> 2;            // 0..127
    const int bq = (tid & 3) * 8;       // 0,8,16,24

    const int koff = (lane >> 4) * 8;   // same k-bijection for A and B frags
    const int fr   = lane & 15;
    const int rowg = (lane >> 4) * 4;

    // ---- hoist epilogue perm loads (latency hides under K-loop) ----
    int pr[2][4];
    #pragma unroll
    for (int mi = 0; mi < 2; ++mi)
        #pragma unroll
        for (int j = 0; j < 4; ++j) {
            int m = m0 + wr * 32 + mi * 16 + rowg + j;
            pr[mi][j] = (m < M) ? pperm[m] : 0;
        }

    f32x4 acc[2][2];
    #pragma unroll
    for (int mi = 0; mi < 2; ++mi)
        #pragma unroll
        for (int ni = 0; ni < 2; ++ni) acc[mi][ni] = (f32x4)0.0f;

    float4 av;
    int4   bv;
#define ISSUE_LOADS(K0)                                                        \
    {                                                                          \
        av = make_float4(0.f, 0.f, 0.f, 0.f);                                  \
        if (avalid && ((K0) + ac) < K)                                         \
            av = *reinterpret_cast<const float4*>(aptr + (K0) + ac);           \
        if (((K0) + bq) < K)                                                   \
            bv = *reinterpret_cast<const int4*>(                               \
                bt + (size_t)(n0 + br) * K + (K0) + bq);                       \
        else bv = make_int4(0, 0, 0, 0);                                       \
    }

    ISSUE_LOADS(0);
    for (int k0 = 0; k0 < K; k0 += 32) {
        __syncthreads();                        // previous tile's frag reads done
        {
            short asv[4];
            asv[0] = f2bf(av.x); asv[1] = f2bf(av.y);
            asv[2] = f2bf(av.z); asv[3] = f2bf(av.w);
            *reinterpret_cast<int2*>(&As[ar][ac]) = *reinterpret_cast<const int2*>(asv);
            *reinterpret_cast<int4*>(&Bs[br][bq]) = bv;
        }
        if (k0 + 32 < K) ISSUE_LOADS(k0 + 32);  // issue-early: hide under MFMA
        __syncthreads();

        bf16x8 afr[2], bfr[2];
        #pragma unroll
        for (int mi = 0; mi < 2; ++mi)
            afr[mi] = *reinterpret_cast<const bf16x8*>(&As[wr * 32 + mi * 16 + fr][koff]);
        #pragma unroll
        for (int ni = 0; ni < 2; ++ni)
            bfr[ni] = *reinterpret_cast<const bf16x8*>(&Bs[wc * 32 + ni * 16 + fr][koff]);
        #pragma unroll
        for (int mi = 0; mi < 2; ++mi)
            #pragma unroll
            for (int ni = 0; ni < 2; ++ni)
                acc[mi][ni] = __builtin_amdgcn_mfma_f32_16x16x32_bf16(
                    afr[mi], bfr[ni], acc[mi][ni], 0, 0, 0);
    }
#undef ISSUE_LOADS

    // ---- epilogue: C/D layout col=lane&15, row=(lane>>4)*4+reg ----
    const int colb = n0 + wc * 32 + fr;
    #pragma unroll
    for (int mi = 0; mi < 2; ++mi) {
        #pragma unroll
        for (int j = 0; j < 4; ++j) {
            int m = m0 + wr * 32 + mi * 16 + rowg + j;
            if (m < M) {
                size_t r = (size_t)pr[mi][j] * DPROJ + colb;
                out[r]      = acc[mi][0][j] * SCALE;
                out[r + 16] = acc[mi][1][j] * SCALE;
            }
        }
    }
}

// ---------------------------------------------------------------------------
// Fallback (ws too small): one block per token, direct fp32 dot products.
// ---------------------------------------------------------------------------
__global__ void k_naive(const int* __restrict__ inp,
                        const float* __restrict__ emb0, const float* __restrict__ emb1,
                        const float* __restrict__ emb2, const float* __restrict__ emb3,
                        const float* __restrict__ proj0, const float* __restrict__ proj1,
                        const float* __restrict__ proj2, const float* __restrict__ proj3,
                        float* __restrict__ out)
{
    __shared__ float e[1024];
    int t = inp[blockIdx.x];
    const float* emb; const float* proj; int K, l;
    if (t < 20000)       { emb = emb0; proj = proj0; K = 1024; l = 0; }
    else if (t < 40000)  { emb = emb1; proj = proj1; K = 256;  l = 20000; }
    else if (t < 200000) { emb = emb2; proj = proj2; K = 64;   l = 40000; }
    else                 { emb = emb3; proj = proj3; K = 16;   l = 200000; }
    int tid = threadIdx.x;
    for (int k = tid; k < K; k += 256) e[k] = emb[(size_t)(t - l) * K + k];
    __syncthreads();
    float acc[4] = {0.f, 0.f, 0.f, 0.f};
    for (int k = 0; k < K; ++k) {
        float ek = e[k];
        #pragma unroll
        for (int c = 0; c < 4; ++c)
            acc[c] = fmaf(ek, proj[(size_t)k * DPROJ + tid + 256 * c], acc[c]);
    }
    #pragma unroll
    for (int c = 0; c < 4; ++c)
        out[(size_t)blockIdx.x * DPROJ + tid + 256 * c] = acc[c] * SCALE;
}

extern "C" void kernel_launch(void* const* d_in, const int* in_sizes, int n_in,
                              void* d_out, int out_size, void* d_ws, size_t ws_size,
                              hipStream_t stream) {
    const int*   inp   = (const int*)d_in[0];
    const float* emb0  = (const float*)d_in[1];
    const float* proj0 = (const float*)d_in[2];
    const float* emb1  = (const float*)d_in[3];
    const float* proj1 = (const float*)d_in[4];
    const float* emb2  = (const float*)d_in[5];
    const float* proj2 = (const float*)d_in[6];
    const float* emb3  = (const float*)d_in[7];
    const float* proj3 = (const float*)d_in[8];
    float* out = (float*)d_out;

    // ws layout (256B-aligned regions)
    const size_t off_cnt  = 0;
    const size_t off_perm = 256;
    const size_t off_row  = off_perm + 4ull * N_TOK * 4;
    const size_t off_t0   = off_row  + 4ull * N_TOK * 4;
    const size_t off_t1   = off_t0 + 1024ull * 1024 * 2;
    const size_t off_t2   = off_t1 + 1024ull * 256 * 2;
    const size_t off_t3   = off_t2 + 1024ull * 64 * 2;
    const size_t needed   = off_t3 + 1024ull * 16 * 2;

    if (d_ws == nullptr || ws_size < needed) {
        k_naive<<<N_TOK, 256, 0, stream>>>(inp, emb0, emb1, emb2, emb3,
                                           proj0, proj1, proj2, proj3, out);
        return;
    }

    char* ws = (char*)d_ws;
    int*   cnt    = (int*)(ws + off_cnt);
    int*   perm   = (int*)(ws + off_perm);
    int*   rowidx = (int*)(ws + off_row);
    short* t0     = (short*)(ws + off_t0);
    short* t1     = (short*)(ws + off_t1);
    short* t2     = (short*)(ws + off_t2);
    short* t3     = (short*)(ws + off_t3);

    hipMemsetAsync(cnt, 0, 16, stream);
    k_prep<<<896, 256, 0, stream>>>(inp, cnt, perm, rowidx,
                                    proj0, proj1, proj2, proj3, t0, t1, t2, t3);

    dim3 grid(8, 520);      // 8 panels x 520 ytiles; 64-chunk bijective XCD remap
    k_gemm<<<grid, 512, 0, stream>>>(emb0, emb1, emb2, emb3,
                                     t0, t1, t2, t3,
                                     cnt, perm, rowidx, out);
}

// Round 10
// 58.938 us; speedup vs baseline: 1.1061x; 1.0057x over previous
//
#include <hip/hip_runtime.h>
#include <hip/hip_bf16.h>

#define N_TOK   32768       // 8 * 4096 tokens
#define DPROJ   1024
#define SCALE   32.0f       // sqrt(1024)

typedef short bf16x8 __attribute__((ext_vector_type(8)));
typedef float f32x4  __attribute__((ext_vector_type(4)));

__device__ __forceinline__ short f2bf(float f) {
    unsigned u = __builtin_bit_cast(unsigned, f);
    unsigned r = (u + 0x7FFFu + ((u >> 16) & 1u)) >> 16;   // RNE
    return (short)r;
}

// ---------------------------------------------------------------------------
// Fused prep kernel.
//   blocks [0,128):   bucketize (wave-ballot aggregated, 4 atomics per wave)
//   blocks [128,896): transpose+convert proj -> projT[n][k] bf16
// ---------------------------------------------------------------------------
__global__ void k_prep(const int* __restrict__ inp, int* __restrict__ cnt,
                       int* __restrict__ perm, int* __restrict__ rowidx,
                       const float* __restrict__ p0, const float* __restrict__ p1,
                       const float* __restrict__ p2, const float* __restrict__ p3,
                       short* __restrict__ t0, short* __restrict__ t1,
                       short* __restrict__ t2, short* __restrict__ t3)
{
    __shared__ float tile[128][17];

    if (blockIdx.x < 128) {
        // ---------------- bucketize ----------------
        int i = blockIdx.x * 256 + threadIdx.x;
        int t = inp[i];
        int b, l;
        if (t < 20000)       { b = 0; l = 0; }
        else if (t < 40000)  { b = 1; l = 20000; }
        else if (t < 200000) { b = 2; l = 40000; }
        else                 { b = 3; l = 200000; }

        unsigned long long m0 = __ballot(b == 0);
        unsigned long long m1 = __ballot(b == 1);
        unsigned long long m2 = __ballot(b == 2);
        unsigned long long m3 = __ballot(b == 3);

        int lane = threadIdx.x & 63;
        int mybase = 0;
        if (lane < 4) {
            unsigned long long mm = (lane == 0) ? m0 : (lane == 1) ? m1 : (lane == 2) ? m2 : m3;
            mybase = atomicAdd(&cnt[lane], __popcll(mm));
        }
        int base = __shfl(mybase, b);
        unsigned long long mine = (b == 0) ? m0 : (b == 1) ? m1 : (b == 2) ? m2 : m3;
        unsigned long long lt = (lane == 0) ? 0ull : (~0ull >> (64 - lane));
        int pos = base + __popcll(mine & lt);
        perm[b * N_TOK + pos]   = i;
        rowidx[b * N_TOK + pos] = t - l;
        return;
    }

    // ---------------- transpose ----------------
    int bid = blockIdx.x - 128;
    const float* src; short* dst; int K; int rel;
    if (bid < 512)      { src = p0; dst = t0; K = 1024; rel = bid; }
    else if (bid < 640) { src = p1; dst = t1; K = 256;  rel = bid - 512; }
    else if (bid < 704) { src = p2; dst = t2; K = 64;   rel = bid - 640; }
    else                { src = p3; dst = t3; K = 16;   rel = bid - 704; }
    int ktiles = (K + 127) >> 7;
    int k0 = (rel % ktiles) * 128;
    int n0 = (rel / ktiles) * 16;
    int t = threadIdx.x;

    #pragma unroll
    for (int i = 0; i < 2; ++i) {
        int idx = t + i * 256;          // 0..511
        int k = idx >> 2;               // 0..127
        int nc = (idx & 3) * 4;         // 0,4,8,12
        if (k0 + k < K) {
            float4 v = *reinterpret_cast<const float4*>(src + (size_t)(k0 + k) * DPROJ + n0 + nc);
            tile[k][nc + 0] = v.x; tile[k][nc + 1] = v.y;
            tile[k][nc + 2] = v.z; tile[k][nc + 3] = v.w;
        }
    }
    __syncthreads();
    int n  = t >> 4;                    // 0..15
    int kc = (t & 15) * 8;              // 0..120
    if (k0 + kc < K) {
        short s[8];
        #pragma unroll
        for (int j = 0; j < 8; ++j) s[j] = f2bf(tile[kc + j][n]);
        *reinterpret_cast<int4*>(dst + (size_t)(n0 + n) * K + k0 + kc) =
            *reinterpret_cast<const int4*>(s);
    }
}

// ---------------------------------------------------------------------------
// Templated GEMM body. 512 threads / 8 waves, BM=64, BN=256, BK=32,
// wave-tile 64x32 (acc[4][2]). Double-buffered LDS, ONE barrier per K-step,
// loads issued 3 steps ahead via two statically-indexed register sets.
// K is compile-time: K=16/64 collapse to straight-line 1/2-stage code.
// ---------------------------------------------------------------------------
template<int K>
__device__ __forceinline__ void gemm_body(
    const float* __restrict__ emb, const short* __restrict__ bt,
    int M, int m0, const int* __restrict__ pperm, const int* __restrict__ prow,
    int n0, float* __restrict__ out,
    short (&As)[2][64][40], short (&Bs)[2][256][40])
{
    constexpr int NSTEP = (K + 31) / 32;

    const int tid  = threadIdx.x;
    const int lane = tid & 63;
    const int w    = tid >> 6;          // 0..7

    // staging indices
    const int ar = tid >> 3;            // 0..63   A row
    const int ac = (tid & 7) * 4;       // 0..28   A k-chunk (4 floats)
    const int br = tid >> 1;            // 0..255  B row
    const int bh = (tid & 1) * 16;      // 0 / 16  B k-chunk (16 shorts)
    const bool avalid = (m0 + ar) < M;
    const int  arow   = avalid ? prow[m0 + ar] : 0;
    const float* aptr = emb + (size_t)arow * K;

    const int koff = (lane >> 4) * 8;   // same k-bijection for A and B frags
    const int fr   = lane & 15;
    const int rowg = (lane >> 4) * 4;

    // hoisted epilogue row permutation (latency hides under K-loop)
    int pr[4][4];
    #pragma unroll
    for (int mi = 0; mi < 4; ++mi)
        #pragma unroll
        for (int j = 0; j < 4; ++j) {
            int m = m0 + mi * 16 + rowg + j;
            pr[mi][j] = (m < M) ? pperm[m] : 0;
        }

    f32x4 acc[4][2];
    #pragma unroll
    for (int mi = 0; mi < 4; ++mi)
        #pragma unroll
        for (int ni = 0; ni < 2; ++ni) acc[mi][ni] = (f32x4)0.0f;

    float4 av0, av1;
    int4   b00, b01, b10, b11;

#define LOADK0(KS)                                                             \
    {                                                                          \
        av0 = make_float4(0.f, 0.f, 0.f, 0.f);                                 \
        if (avalid && (K >= 32 || ac < K))                                     \
            av0 = *reinterpret_cast<const float4*>(aptr + (KS) * 32 + ac);     \
        if (K >= 32 || bh < K) {                                               \
            const short* bp = bt + (size_t)(n0 + br) * K + (KS) * 32 + bh;     \
            b00 = *reinterpret_cast<const int4*>(bp);                          \
            b01 = *reinterpret_cast<const int4*>(bp + 8);                      \
        } else { b00 = make_int4(0,0,0,0); b01 = make_int4(0,0,0,0); }         \
    }
#define LOADK1(KS)                                                             \
    {                                                                          \
        av1 = make_float4(0.f, 0.f, 0.f, 0.f);                                 \
        if (avalid && (K >= 32 || ac < K))                                     \
            av1 = *reinterpret_cast<const float4*>(aptr + (KS) * 32 + ac);     \
        if (K >= 32 || bh < K) {                                               \
            const short* bp = bt + (size_t)(n0 + br) * K + (KS) * 32 + bh;     \
            b10 = *reinterpret_cast<const int4*>(bp);                          \
            b11 = *reinterpret_cast<const int4*>(bp + 8);                      \
        } else { b10 = make_int4(0,0,0,0); b11 = make_int4(0,0,0,0); }         \
    }
#define WRITEK(CUR, AV, B0, B1)                                                \
    {                                                                          \
        short asv[4];                                                          \
        asv[0] = f2bf((AV).x); asv[1] = f2bf((AV).y);                          \
        asv[2] = f2bf((AV).z); asv[3] = f2bf((AV).w);                          \
        *reinterpret_cast<int2*>(&As[CUR][ar][ac]) =                           \
            *reinterpret_cast<const int2*>(asv);                               \
        *reinterpret_cast<int4*>(&Bs[CUR][br][bh])     = (B0);                 \
        *reinterpret_cast<int4*>(&Bs[CUR][br][bh + 8]) = (B1);                 \
    }
#define MFMAK(CUR)                                                             \
    {                                                                          \
        bf16x8 afr[4], bfr[2];                                                 \
        _Pragma("unroll")                                                      \
        for (int mi = 0; mi < 4; ++mi)                                         \
            afr[mi] = *reinterpret_cast<const bf16x8*>(                        \
                &As[CUR][mi * 16 + fr][koff]);                                 \
        _Pragma("unroll")                                                      \
        for (int ni = 0; ni < 2; ++ni)                                         \
            bfr[ni] = *reinterpret_cast<const bf16x8*>(                        \
                &Bs[CUR][w * 32 + ni * 16 + fr][koff]);                        \
        _Pragma("unroll")                                                      \
        for (int mi = 0; mi < 4; ++mi)                                         \
            _Pragma("unroll")                                                  \
            for (int ni = 0; ni < 2; ++ni)                                     \
                acc[mi][ni] = __builtin_amdgcn_mfma_f32_16x16x32_bf16(         \
                    afr[mi], bfr[ni], acc[mi][ni], 0, 0, 0);                   \
    }

    if constexpr (NSTEP == 1) {
        LOADK0(0);
        WRITEK(0, av0, b00, b01);
        __syncthreads();
        MFMAK(0);
    } else {
        // prologue: LDS[0] <- step0; set0 <- step1; set1 <- step2
        LOADK0(0);
        WRITEK(0, av0, b00, b01);
        LOADK0(1);
        if constexpr (NSTEP > 2) LOADK1(2);
        __syncthreads();

        for (int k = 0; k < NSTEP; k += 2) {
            // ---- step k (cur=0): set0 holds data(k+1) ----
            if (k + 1 < NSTEP) WRITEK(1, av0, b00, b01);
            if (k + 3 < NSTEP) LOADK0(k + 3);
            MFMAK(0);
            __syncthreads();
            // ---- step k+1 (cur=1): set1 holds data(k+2) ----
            if (k + 1 < NSTEP) {
                if (k + 2 < NSTEP) WRITEK(0, av1, b10, b11);
                if (k + 4 < NSTEP) LOADK1(k + 4);
                MFMAK(1);
                __syncthreads();
            }
        }
    }
#undef LOADK0
#undef LOADK1
#undef WRITEK
#undef MFMAK

    // ---- epilogue: C/D layout col=lane&15, row=(lane>>4)*4+reg ----
    const int colb = n0 + w * 32 + fr;
    #pragma unroll
    for (int mi = 0; mi < 4; ++mi) {
        #pragma unroll
        for (int j = 0; j < 4; ++j) {
            int m = m0 + mi * 16 + rowg + j;
            if (m < M) {
                size_t r = (size_t)pr[mi][j] * DPROJ + colb;
                out[r]      = acc[mi][0][j] * SCALE;
                out[r + 16] = acc[mi][1][j] * SCALE;
            }
        }
    }
}

// ---------------------------------------------------------------------------
// Fused gathered bf16-MFMA GEMM over all buckets (K-templated dispatch).
// Grid 4x520, XCD remap: all 4 n-panels of a row-tile on the same XCD.
// ---------------------------------------------------------------------------
__global__ __launch_bounds__(512, 4) void k_gemm(
    const float* __restrict__ e0, const float* __restrict__ e1,
    const float* __restrict__ e2, const float* __restrict__ e3,
    const short* __restrict__ t0, const short* __restrict__ t1,
    const short* __restrict__ t2, const short* __restrict__ t3,
    const int* __restrict__ cnt, const int* __restrict__ perm,
    const int* __restrict__ rowidx, float* __restrict__ out)
{
    __shared__ short As[2][64][40];     // 10.2 KB
    __shared__ short Bs[2][256][40];    // 41.0 KB

    // ---- dispatch-id -> (ytile, panel), XCD-grouped ----
    const int hw    = blockIdx.y * 4 + blockIdx.x;    // HW dispatch order (x fastest)
    const int ytile = (hw >> 5) * 8 + (hw & 7);
    const int panel = (hw >> 3) & 3;

    const int c0 = cnt[0], c1 = cnt[1], c2 = cnt[2], c3 = cnt[3];
    const int q0 = (c0 + 63) & ~63;
    const int q1 = q0 + ((c1 + 63) & ~63);
    const int q2 = q1 + ((c2 + 63) & ~63);
    const int q3 = q2 + ((c3 + 63) & ~63);
    const int p0 = ytile * 64;
    if (p0 >= q3) return;
    const int n0 = panel * 256;

    if (p0 < q0) {
        if (p0 >= c0) return;
        gemm_body<1024>(e0, t0, c0, p0, perm, rowidx, n0, out, As, Bs);
    } else if (p0 < q1) {
        int m0 = p0 - q0;
        if (m0 >= c1) return;
        gemm_body<256>(e1, t1, c1, m0, perm + N_TOK, rowidx + N_TOK, n0, out, As, Bs);
    } else if (p0 < q2) {
        int m0 = p0 - q1;
        if (m0 >= c2) return;
        gemm_body<64>(e2, t2, c2, m0, perm + 2 * N_TOK, rowidx + 2 * N_TOK, n0, out, As, Bs);
    } else {
        int m0 = p0 - q2;
        if (m0 >= c3) return;
        gemm_body<16>(e3, t3, c3, m0, perm + 3 * N_TOK, rowidx + 3 * N_TOK, n0, out, As, Bs);
    }
}

// ---------------------------------------------------------------------------
// Fallback (ws too small): one block per token, direct fp32 dot products.
// ---------------------------------------------------------------------------
__global__ void k_naive(const int* __restrict__ inp,
                        const float* __restrict__ emb0, const float* __restrict__ emb1,
                        const float* __restrict__ emb2, const float* __restrict__ emb3,
                        const float* __restrict__ proj0, const float* __restrict__ proj1,
                        const float* __restrict__ proj2, const float* __restrict__ proj3,
                        float* __restrict__ out)
{
    __shared__ float e[1024];
    int t = inp[blockIdx.x];
    const float* emb; const float* proj; int K, l;
    if (t < 20000)       { emb = emb0; proj = proj0; K = 1024; l = 0; }
    else if (t < 40000)  { emb = emb1; proj = proj1; K = 256;  l = 20000; }
    else if (t < 200000) { emb = emb2; proj = proj2; K = 64;   l = 40000; }
    else                 { emb = emb3; proj = proj3; K = 16;   l = 200000; }
    int tid = threadIdx.x;
    for (int k = tid; k < K; k += 256) e[k] = emb[(size_t)(t - l) * K + k];
    __syncthreads();
    float acc[4] = {0.f, 0.f, 0.f, 0.f};
    for (int k = 0; k < K; ++k) {
        float ek = e[k];
        #pragma unroll
        for (int c = 0; c < 4; ++c)
            acc[c] = fmaf(ek, proj[(size_t)k * DPROJ + tid + 256 * c], acc[c]);
    }
    #pragma unroll
    for (int c = 0; c < 4; ++c)
        out[(size_t)blockIdx.x * DPROJ + tid + 256 * c] = acc[c] * SCALE;
}

extern "C" void kernel_launch(void* const* d_in, const int* in_sizes, int n_in,
                              void* d_out, int out_size, void* d_ws, size_t ws_size,
                              hipStream_t stream) {
    const int*   inp   = (const int*)d_in[0];
    const float* emb0  = (const float*)d_in[1];
    const float* proj0 = (const float*)d_in[2];
    const float* emb1  = (const float*)d_in[3];
    const float* proj1 = (const float*)d_in[4];
    const float* emb2  = (const float*)d_in[5];
    const float* proj2 = (const float*)d_in[6];
    const float* emb3  = (const float*)d_in[7];
    const float* proj3 = (const float*)d_in[8];
    float* out = (float*)d_out;

    // ws layout (256B-aligned regions)
    const size_t off_cnt  = 0;
    const size_t off_perm = 256;
    const size_t off_row  = off_perm + 4ull * N_TOK * 4;
    const size_t off_t0   = off_row  + 4ull * N_TOK * 4;
    const size_t off_t1   = off_t0 + 1024ull * 1024 * 2;
    const size_t off_t2   = off_t1 + 1024ull * 256 * 2;
    const size_t off_t3   = off_t2 + 1024ull * 64 * 2;
    const size_t needed   = off_t3 + 1024ull * 16 * 2;

    if (d_ws == nullptr || ws_size < needed) {
        k_naive<<<N_TOK, 256, 0, stream>>>(inp, emb0, emb1, emb2, emb3,
                                           proj0, proj1, proj2, proj3, out);
        return;
    }

    char* ws = (char*)d_ws;
    int*   cnt    = (int*)(ws + off_cnt);
    int*   perm   = (int*)(ws + off_perm);
    int*   rowidx = (int*)(ws + off_row);
    short* t0     = (short*)(ws + off_t0);
    short* t1     = (short*)(ws + off_t1);
    short* t2     = (short*)(ws + off_t2);
    short* t3     = (short*)(ws + off_t3);

    hipMemsetAsync(cnt, 0, 16, stream);
    k_prep<<<896, 256, 0, stream>>>(inp, cnt, perm, rowidx,
                                    proj0, proj1, proj2, proj3, t0, t1, t2, t3);

    dim3 grid(4, 520);      // 4*520 = 2080 = 65 complete mod-8 chunks (bijective remap)
    k_gemm<<<grid, 512, 0, stream>>>(emb0, emb1, emb2, emb3,
                                     t0, t1, t2, t3,
                                     cnt, perm, rowidx, out);
}